// Round 23
// baseline (149.945 us; speedup 1.0000x reference)
//
#include <hip/hip_runtime.h>

#define N_NODES 20000
#define D_FEAT 256
#define N_SUPPORT 3
#define N_EDGES 320000
#define OUT_DIM 256
#define TOTAL_E (N_SUPPORT * N_EDGES)
#define NWIN 8
#define LWORDS 16                   // one 64B line: [count][15 records]
#define CAPX 15                     // records per sub-bucket; lambda=2, P(>15)~3e-10
#define KDIM (N_SUPPORT * D_FEAT)   // 768
#define NBUCKET (N_SUPPORT * N_NODES)  // 60000
#define GM_ROWS 128
#define GM_BLOCKS ((N_NODES + GM_ROWS - 1) / GM_ROWS)   // 157

typedef __attribute__((ext_vector_type(8))) short short8;
typedef __attribute__((ext_vector_type(8))) unsigned short ushort8;
typedef __attribute__((ext_vector_type(4))) float f32x4;

__device__ inline unsigned short f2bf(float f) {
    unsigned int u = __float_as_uint(f);
    u += 0x7fff + ((u >> 16) & 1);  // round-to-nearest-even
    return (unsigned short)(u >> 16);
}

// ---------------- prep1: quantize_x (4 rows/wave, ILP-4) | convert_w (r21-verified) ----------------
#define NB_X (N_NODES / 16)         // 1250 blocks, 4 waves, 4 rows/wave
#define NB_W (N_SUPPORT * D_FEAT)   // 768
#define NB_F (TOTAL_E / 256)        // 3750

__global__ void __launch_bounds__(256) prep1(const float* __restrict__ x, const float* __restrict__ W,
        unsigned int* __restrict__ xq, float* __restrict__ scl, unsigned short* __restrict__ wt) {
    const int bid = blockIdx.x;
    const int tid = threadIdx.x;
    if (bid < NB_X) {
        const int wid = tid >> 6;
        const int lane = tid & 63;
        const int row0 = bid * 16 + wid * 4;
        float4 v[4];
        float m[4];
#pragma unroll
        for (int r = 0; r < 4; ++r) {
            v[r] = ((const float4*)x)[(size_t)(row0 + r) * 64 + lane];
            m[r] = fmaxf(fmaxf(fabsf(v[r].x), fabsf(v[r].y)), fmaxf(fabsf(v[r].z), fabsf(v[r].w)));
        }
#pragma unroll
        for (int d = 1; d < 64; d <<= 1) {
#pragma unroll
            for (int r = 0; r < 4; ++r) m[r] = fmaxf(m[r], __shfl_xor(m[r], d, 64));
        }
#pragma unroll
        for (int r = 0; r < 4; ++r) {
            const float inv = (m[r] > 0.f) ? 127.0f / m[r] : 0.f;
            int q0 = (int)rintf(v[r].x * inv) + 128;
            int q1 = (int)rintf(v[r].y * inv) + 128;
            int q2 = (int)rintf(v[r].z * inv) + 128;
            int q3 = (int)rintf(v[r].w * inv) + 128;
            unsigned int pk = (unsigned int)q0 | ((unsigned int)q1 << 8)
                            | ((unsigned int)q2 << 16) | ((unsigned int)q3 << 24);
            xq[(size_t)(row0 + r) * 64 + lane] = pk;
            if (lane == 0) scl[row0 + r] = m[r] * (1.0f / 127.0f);
        }
    } else {
        const int row = bid - NB_X;        // s*256 + k
        const int s = row >> 8, k = row & 255;
        wt[((size_t)s * OUT_DIM + tid) * D_FEAT + k] = f2bf(W[(size_t)row * OUT_DIM + tid]);
    }
}

// ---------------- fill_win: count-in-line sub-buckets, window-major (single-writer lines) ----------------
// ep1[win][bucket] = one 64B line: word0 = count (atomic), words 1..15 = records.
// win = blockIdx.x & 7 -> each window region written by one XCD (r21-verified property);
// atomic and record write hit the SAME line.
__global__ void __launch_bounds__(256) fill_win(const int* __restrict__ src,
        const int* __restrict__ dst, const float* __restrict__ w, const float* __restrict__ scl,
        unsigned int* __restrict__ ep1) {
    const int i = blockIdx.x * 256 + threadIdx.x;
    if (i >= TOTAL_E) return;
    const int win = blockIdx.x & (NWIN - 1);
    const int s = i / N_EDGES;
    const int sv = src[i];
    const int b = s * N_NODES + dst[i];
    unsigned int* line = ep1 + ((size_t)win * NBUCKET + b) * LWORDS;
    const unsigned int pos = atomicAdd(line, 1u);
    if (pos < CAPX) {
        const float wq = w[i] * scl[sv];
        line[1 + pos] = (unsigned int)sv | (((unsigned int)f2bf(wq)) << 16);
    }
}

// ---------------- aggregate: fused; one 32-lane half per bucket; UNIFORM branches ----------------
// cnt is identical across the half-wave (same bucket) -> all branches are scalar,
// no padding needed (r22 lesson). 8 independent head loads in flight.
#define PROC(p) {                                                              \
    const unsigned int sv_ = (p) & 0xFFFFu;                                    \
    const uint2 u_ = *(const uint2*)(xq + ((size_t)sv_ << 8) + xoff);          \
    const float wv_ = __uint_as_float((p) & 0xFFFF0000u);                      \
    sw += wv_;                                                                 \
    _Pragma("unroll")                                                          \
    for (int j = 0; j < 4; ++j) {                                              \
        const int sh = 8 * j;                                                  \
        a[j]     += wv_ * (float)((u_.x >> sh) & 0xffu);                       \
        a[4 + j] += wv_ * (float)((u_.y >> sh) & 0xffu);                       \
    }                                                                          \
}

__global__ void __launch_bounds__(256) aggregate(
        const unsigned char* __restrict__ xq, const unsigned int* __restrict__ ep1,
        unsigned short* __restrict__ hb) {
    const int b = blockIdx.x * 8 + (threadIdx.x >> 5);
    const int l32 = threadIdx.x & 31;
    const int xoff = l32 * 8;
    const int s = b / N_NODES;
    const int node = b - s * N_NODES;

    // preload 8 window line-heads: count + first 3 records each, 8 loads in flight
    uint4 h0[NWIN];
#pragma unroll
    for (int w = 0; w < NWIN; ++w)
        h0[w] = *(const uint4*)(ep1 + ((size_t)w * NBUCKET + b) * LWORDS);

    float a[8];
#pragma unroll
    for (int j = 0; j < 8; ++j) a[j] = 0.f;
    float sw = 0.f;

#pragma unroll
    for (int w = 0; w < NWIN; ++w) {
        unsigned int cnt = h0[w].x; if (cnt > CAPX) cnt = CAPX;
        // records 1..3 live in the preloaded head
        if (cnt > 0) PROC(h0[w].y);
        if (cnt > 1) PROC(h0[w].z);
        if (cnt > 2) PROC(h0[w].w);
        if (cnt > 3) {                 // P ~ 0.14 per window (Poisson lambda=2)
            const unsigned int* lp = ep1 + ((size_t)w * NBUCKET + b) * LWORDS + 4;
            uint4 t = *(const uint4*)lp;
            PROC(t.x);
            if (cnt > 4) PROC(t.y);
            if (cnt > 5) PROC(t.z);
            if (cnt > 6) PROC(t.w);
            if (cnt > 7) {
                uint4 t2 = *(const uint4*)(lp + 4);
                PROC(t2.x);
                if (cnt > 8) PROC(t2.y);
                if (cnt > 9) PROC(t2.z);
                if (cnt > 10) PROC(t2.w);
                if (cnt > 11) {
                    uint4 t3 = *(const uint4*)(lp + 8);
                    PROC(t3.x);
                    if (cnt > 12) PROC(t3.y);
                    if (cnt > 13) PROC(t3.z);
                    if (cnt > 14) PROC(t3.w);
                }
            }
        }
    }

    ushort8 o;
    const float bias = 128.f * sw;
#pragma unroll
    for (int j = 0; j < 8; ++j) o[j] = f2bf(a[j] - bias);
    *(ushort8*)(hb + (size_t)node * KDIM + s * D_FEAT + xoff) = o;
}

// ---------------- gemm_h: BM=128 tile, LDS-staged B (unchanged, verified) ----------------
__global__ void __launch_bounds__(512) gemm_h(
        const unsigned short* __restrict__ hb, const unsigned short* __restrict__ wt,
        float* __restrict__ out) {
    __shared__ unsigned short bs[OUT_DIM][136];
    const int n0 = blockIdx.x * GM_ROWS;
    const int wid = threadIdx.x >> 6;
    const int lane = threadIdx.x & 63;
    const int cit = lane & 15;
    const int kgrp = (lane >> 4) * 8;
    const bool valid = (n0 + wid * 16) < N_NODES;
    const int arow_idx = valid ? (n0 + wid * 16 + cit) : 0;
    const short* arow = (const short*)hb + (size_t)arow_idx * KDIM + kgrp;

    f32x4 acc[16];
#pragma unroll
    for (int j = 0; j < 16; ++j) acc[j] = (f32x4){0.f, 0.f, 0.f, 0.f};

    for (int kc = 0; kc < 6; ++kc) {
        const int s = kc >> 1;
        const int kb = (kc & 1) * 128;
        if (kc) __syncthreads();
        for (int i = threadIdx.x; i < 4096; i += 512) {
            const int n = i >> 4;
            const int k8 = (i & 15) << 3;
            *(ushort8*)&bs[n][k8] =
                *(const ushort8*)(wt + ((size_t)s * OUT_DIM + n) * D_FEAT + kb + k8);
        }
        __syncthreads();

#pragma unroll
        for (int ks = 0; ks < 4; ++ks) {
            short8 av = *(const short8*)(arow + kc * 128 + ks * 32);
#pragma unroll
            for (int nt = 0; nt < 16; ++nt) {
                short8 bv = *(const short8*)&bs[nt * 16 + cit][ks * 32 + kgrp];
                acc[nt] = __builtin_amdgcn_mfma_f32_16x16x32_bf16(av, bv, acc[nt], 0, 0, 0);
            }
        }
    }

    if (valid) {
        const int rbase = (lane >> 4) * 4;
#pragma unroll
        for (int nt = 0; nt < 16; ++nt) {
            const int col = nt * 16 + cit;
#pragma unroll
            for (int r = 0; r < 4; ++r) {
                out[(size_t)(n0 + wid * 16 + rbase + r) * OUT_DIM + col] = acc[nt][r];
            }
        }
    }
}

extern "C" void kernel_launch(void* const* d_in, const int* in_sizes, int n_in,
                              void* d_out, int out_size, void* d_ws, size_t ws_size,
                              hipStream_t stream) {
    const float* x        = (const float*)d_in[0];
    const int*   edge_src = (const int*)d_in[1];
    const int*   edge_dst = (const int*)d_in[2];
    const float* edge_w   = (const float*)d_in[3];
    const float* W        = (const float*)d_in[4];
    float* out = (float*)d_out;

    char* ws = (char*)d_ws;
    unsigned int*   xq    = (unsigned int*)(ws);                 //  5,120,000 B
    float*          scl   = (float*)(ws + 5120000);              //     80,000 B
    unsigned short* wt    = (unsigned short*)(ws + 5200000);     //    393,216 B
    unsigned int*   ep1   = (unsigned int*)(ws + 5593216);       // 30,720,000 B ([8][60000][16])
    unsigned short* hb    = (unsigned short*)(ws + 36313216);    // 30,720,000 B
    // total: 67,033,216 B

    hipMemsetAsync(ep1, 0, 30720000, stream);   // zeroes all line counts (and records)

    prep1<<<NB_X + NB_W, 256, 0, stream>>>(x, W, xq, scl, wt);
    fill_win<<<NB_F, 256, 0, stream>>>(edge_src, edge_dst, edge_w, scl, ep1);

    aggregate<<<NBUCKET / 8, 256, 0, stream>>>((const unsigned char*)xq, ep1, hb);

    gemm_h<<<GM_BLOCKS, 512, 0, stream>>>(hb, wt, out);
}

// Round 24
// 145.380 us; speedup vs baseline: 1.0314x; 1.0314x over previous
//
#include <hip/hip_runtime.h>

#define N_NODES 20000
#define D_FEAT 256
#define N_SUPPORT 3
#define N_EDGES 320000
#define OUT_DIM 256
#define TOTAL_E (N_SUPPORT * N_EDGES)
#define CAPX 16                     // per-(bucket,window) capacity; lambda=2, P(>16)~1e-11
#define NWIN 8
#define KDIM (N_SUPPORT * D_FEAT)   // 768
#define NBUCKET (N_SUPPORT * N_NODES)  // 60000
#define GM_ROWS 128
#define GM_BLOCKS ((N_NODES + GM_ROWS - 1) / GM_ROWS)   // 157

typedef __attribute__((ext_vector_type(8))) short short8;
typedef __attribute__((ext_vector_type(8))) unsigned short ushort8;
typedef __attribute__((ext_vector_type(4))) float f32x4;

__device__ inline unsigned short f2bf(float f) {
    unsigned int u = __float_as_uint(f);
    u += 0x7fff + ((u >> 16) & 1);  // round-to-nearest-even
    return (unsigned short)(u >> 16);
}

// ---------------- prep1: quantize_x (4 rows/wave, ILP-4) | convert_w (r21-verified) ----------------
#define NB_X (N_NODES / 16)         // 1250 blocks, 4 waves, 4 rows/wave
#define NB_W (N_SUPPORT * D_FEAT)   // 768
#define NB_F (TOTAL_E / 256)        // 3750

__global__ void __launch_bounds__(256) prep1(const float* __restrict__ x, const float* __restrict__ W,
        unsigned int* __restrict__ xq, float* __restrict__ scl, unsigned short* __restrict__ wt) {
    const int bid = blockIdx.x;
    const int tid = threadIdx.x;
    if (bid < NB_X) {
        const int wid = tid >> 6;
        const int lane = tid & 63;
        const int row0 = bid * 16 + wid * 4;
        float4 v[4];
        float m[4];
#pragma unroll
        for (int r = 0; r < 4; ++r) {
            v[r] = ((const float4*)x)[(size_t)(row0 + r) * 64 + lane];
            m[r] = fmaxf(fmaxf(fabsf(v[r].x), fabsf(v[r].y)), fmaxf(fabsf(v[r].z), fabsf(v[r].w)));
        }
#pragma unroll
        for (int d = 1; d < 64; d <<= 1) {
#pragma unroll
            for (int r = 0; r < 4; ++r) m[r] = fmaxf(m[r], __shfl_xor(m[r], d, 64));
        }
#pragma unroll
        for (int r = 0; r < 4; ++r) {
            const float inv = (m[r] > 0.f) ? 127.0f / m[r] : 0.f;
            int q0 = (int)rintf(v[r].x * inv) + 128;
            int q1 = (int)rintf(v[r].y * inv) + 128;
            int q2 = (int)rintf(v[r].z * inv) + 128;
            int q3 = (int)rintf(v[r].w * inv) + 128;
            unsigned int pk = (unsigned int)q0 | ((unsigned int)q1 << 8)
                            | ((unsigned int)q2 << 16) | ((unsigned int)q3 << 24);
            xq[(size_t)(row0 + r) * 64 + lane] = pk;
            if (lane == 0) scl[row0 + r] = m[r] * (1.0f / 127.0f);
        }
    } else {
        const int row = bid - NB_X;        // s*256 + k
        const int s = row >> 8, k = row & 255;
        wt[((size_t)s * OUT_DIM + tid) * D_FEAT + k] = f2bf(W[(size_t)row * OUT_DIM + tid]);
    }
}

// ---------------- fill_win: r21-verbatim (measured 48 us) ----------------
// window-major: cur8[win][b], ep1[win][b][CAPX]; win = blockIdx.x & 7 -> each
// window region written by one XCD under round-robin dispatch.
__global__ void __launch_bounds__(256) fill_win(const int* __restrict__ src,
        const int* __restrict__ dst, const float* __restrict__ w, const float* __restrict__ scl,
        int* __restrict__ cur8, unsigned int* __restrict__ ep1) {
    const int i = blockIdx.x * 256 + threadIdx.x;
    if (i >= TOTAL_E) return;
    const int win = blockIdx.x & (NWIN - 1);
    const int s = i / N_EDGES;
    const int sv = src[i];
    const int b = s * N_NODES + dst[i];
    const int pos = atomicAdd(&cur8[win * NBUCKET + b], 1);
    if (pos < CAPX) {
        const float wq = w[i] * scl[sv];
        ep1[((size_t)win * NBUCKET + b) * CAPX + pos] =
            (unsigned int)sv | (((unsigned int)f2bf(wq)) << 16);
    }
}

// ---------------- aggregate: fused compact+gather; UNIFORM branches (r22 lesson) ----------------
// One 32-lane half per bucket. 8 count loads + 8 record-head loads in flight;
// cnt uniform across the half-wave -> scalar branches, no padding.
#define PROC(p) {                                                              \
    const unsigned int sv_ = (p) & 0xFFFFu;                                    \
    const uint2 u_ = *(const uint2*)(xq + ((size_t)sv_ << 8) + xoff);          \
    const float wv_ = __uint_as_float((p) & 0xFFFF0000u);                      \
    sw += wv_;                                                                 \
    _Pragma("unroll")                                                          \
    for (int j = 0; j < 4; ++j) {                                              \
        const int sh = 8 * j;                                                  \
        a[j]     += wv_ * (float)((u_.x >> sh) & 0xffu);                       \
        a[4 + j] += wv_ * (float)((u_.y >> sh) & 0xffu);                       \
    }                                                                          \
}

__global__ void __launch_bounds__(256) aggregate(
        const unsigned char* __restrict__ xq, const int* __restrict__ cur8,
        const unsigned int* __restrict__ ep1, unsigned short* __restrict__ hb) {
    const int b = blockIdx.x * 8 + (threadIdx.x >> 5);
    const int l32 = threadIdx.x & 31;
    const int xoff = l32 * 8;
    const int s = b / N_NODES;
    const int node = b - s * N_NODES;

    // 8 independent count loads (window-major; 8 consecutive buckets share lines -> L1-hot)
    int c[NWIN];
#pragma unroll
    for (int w = 0; w < NWIN; ++w) {
        int cc = cur8[w * NBUCKET + b];
        c[w] = (cc > CAPX) ? CAPX : cc;
    }

    // preload first 4 records of each window: 8 independent 16B loads in flight
    uint4 g[NWIN];
#pragma unroll
    for (int w = 0; w < NWIN; ++w)
        g[w] = *(const uint4*)(ep1 + ((size_t)w * NBUCKET + b) * CAPX);

    float a[8];
#pragma unroll
    for (int j = 0; j < 8; ++j) a[j] = 0.f;
    float sw = 0.f;

#pragma unroll
    for (int w = 0; w < NWIN; ++w) {
        const int cw = c[w];
        if (cw > 0) PROC(g[w].x);
        if (cw > 1) PROC(g[w].y);
        if (cw > 2) PROC(g[w].z);
        if (cw > 3) PROC(g[w].w);
        if (cw > 4) {                  // P ~ 0.05 (Poisson lambda=2)
            const unsigned int* lp = ep1 + ((size_t)w * NBUCKET + b) * CAPX + 4;
            uint4 t = *(const uint4*)lp;
            PROC(t.x);
            if (cw > 5) PROC(t.y);
            if (cw > 6) PROC(t.z);
            if (cw > 7) PROC(t.w);
            if (cw > 8) {
                uint4 t2 = *(const uint4*)(lp + 4);
                PROC(t2.x);
                if (cw > 9) PROC(t2.y);
                if (cw > 10) PROC(t2.z);
                if (cw > 11) PROC(t2.w);
                if (cw > 12) {
                    uint4 t3 = *(const uint4*)(lp + 8);
                    PROC(t3.x);
                    if (cw > 13) PROC(t3.y);
                    if (cw > 14) PROC(t3.z);
                    if (cw > 15) PROC(t3.w);
                }
            }
        }
    }

    ushort8 o;
    const float bias = 128.f * sw;
#pragma unroll
    for (int j = 0; j < 8; ++j) o[j] = f2bf(a[j] - bias);
    *(ushort8*)(hb + (size_t)node * KDIM + s * D_FEAT + xoff) = o;
}

// ---------------- gemm_h: BM=128 tile, LDS-staged B (unchanged, verified) ----------------
__global__ void __launch_bounds__(512) gemm_h(
        const unsigned short* __restrict__ hb, const unsigned short* __restrict__ wt,
        float* __restrict__ out) {
    __shared__ unsigned short bs[OUT_DIM][136];
    const int n0 = blockIdx.x * GM_ROWS;
    const int wid = threadIdx.x >> 6;
    const int lane = threadIdx.x & 63;
    const int cit = lane & 15;
    const int kgrp = (lane >> 4) * 8;
    const bool valid = (n0 + wid * 16) < N_NODES;
    const int arow_idx = valid ? (n0 + wid * 16 + cit) : 0;
    const short* arow = (const short*)hb + (size_t)arow_idx * KDIM + kgrp;

    f32x4 acc[16];
#pragma unroll
    for (int j = 0; j < 16; ++j) acc[j] = (f32x4){0.f, 0.f, 0.f, 0.f};

    for (int kc = 0; kc < 6; ++kc) {
        const int s = kc >> 1;
        const int kb = (kc & 1) * 128;
        if (kc) __syncthreads();
        for (int i = threadIdx.x; i < 4096; i += 512) {
            const int n = i >> 4;
            const int k8 = (i & 15) << 3;
            *(ushort8*)&bs[n][k8] =
                *(const ushort8*)(wt + ((size_t)s * OUT_DIM + n) * D_FEAT + kb + k8);
        }
        __syncthreads();

#pragma unroll
        for (int ks = 0; ks < 4; ++ks) {
            short8 av = *(const short8*)(arow + kc * 128 + ks * 32);
#pragma unroll
            for (int nt = 0; nt < 16; ++nt) {
                short8 bv = *(const short8*)&bs[nt * 16 + cit][ks * 32 + kgrp];
                acc[nt] = __builtin_amdgcn_mfma_f32_16x16x32_bf16(av, bv, acc[nt], 0, 0, 0);
            }
        }
    }

    if (valid) {
        const int rbase = (lane >> 4) * 4;
#pragma unroll
        for (int nt = 0; nt < 16; ++nt) {
            const int col = nt * 16 + cit;
#pragma unroll
            for (int r = 0; r < 4; ++r) {
                out[(size_t)(n0 + wid * 16 + rbase + r) * OUT_DIM + col] = acc[nt][r];
            }
        }
    }
}

extern "C" void kernel_launch(void* const* d_in, const int* in_sizes, int n_in,
                              void* d_out, int out_size, void* d_ws, size_t ws_size,
                              hipStream_t stream) {
    const float* x        = (const float*)d_in[0];
    const int*   edge_src = (const int*)d_in[1];
    const int*   edge_dst = (const int*)d_in[2];
    const float* edge_w   = (const float*)d_in[3];
    const float* W        = (const float*)d_in[4];
    float* out = (float*)d_out;

    char* ws = (char*)d_ws;
    unsigned int*   xq    = (unsigned int*)(ws);                 //  5,120,000 B
    float*          scl   = (float*)(ws + 5120000);              //     80,000 B
    unsigned short* wt    = (unsigned short*)(ws + 5200000);     //    393,216 B
    int*            cur8  = (int*)(ws + 5593216);                //  1,920,000 B ([win][b])
    unsigned int*   ep1   = (unsigned int*)(ws + 7513216);       // 30,720,000 B ([win][b][16])
    unsigned short* hb    = (unsigned short*)(ws + 38233216);    // 30,720,000 B
    // total: 68,953,216 B

    hipMemsetAsync(cur8, 0, 1920000, stream);

    prep1<<<NB_X + NB_W, 256, 0, stream>>>(x, W, xq, scl, wt);
    fill_win<<<NB_F, 256, 0, stream>>>(edge_src, edge_dst, edge_w, scl, cur8, ep1);

    aggregate<<<NBUCKET / 8, 256, 0, stream>>>((const unsigned char*)xq, cur8, ep1, hb);

    gemm_h<<<GM_BLOCKS, 512, 0, stream>>>(hb, wt, out);
}

// Round 25
// 129.579 us; speedup vs baseline: 1.1572x; 1.1219x over previous
//
#include <hip/hip_runtime.h>

#define N_NODES 20000
#define D_FEAT 256
#define N_SUPPORT 3
#define N_EDGES 320000
#define OUT_DIM 256
#define TOTAL_E (N_SUPPORT * N_EDGES)
#define CAP 64                      // compacted per-bucket capacity
#define CAPX 16                     // per-(bucket,window) capacity; lambda=2 exact
#define NWIN 8
#define KDIM (N_SUPPORT * D_FEAT)   // 768
#define NBUCKET (N_SUPPORT * N_NODES)  // 60000
#define GM_ROWS 128
#define GM_BLOCKS ((N_NODES + GM_ROWS - 1) / GM_ROWS)   // 157

typedef __attribute__((ext_vector_type(8))) short short8;
typedef __attribute__((ext_vector_type(8))) unsigned short ushort8;
typedef __attribute__((ext_vector_type(4))) float f32x4;

__device__ inline unsigned short f2bf(float f) {
    unsigned int u = __float_as_uint(f);
    u += 0x7fff + ((u >> 16) & 1);  // round-to-nearest-even
    return (unsigned short)(u >> 16);
}

// ---------------- prep1: quantize_x (4 rows/wave, ILP-4) | convert_w ----------------
#define NB_X (N_NODES / 16)         // 1250 blocks, 4 waves, 4 rows/wave
#define NB_W (N_SUPPORT * D_FEAT)   // 768
#define NB_F (TOTAL_E / 256)        // 3750

__global__ void __launch_bounds__(256) prep1(const float* __restrict__ x, const float* __restrict__ W,
        unsigned int* __restrict__ xq, float* __restrict__ scl, unsigned short* __restrict__ wt) {
    const int bid = blockIdx.x;
    const int tid = threadIdx.x;
    if (bid < NB_X) {
        const int wid = tid >> 6;
        const int lane = tid & 63;
        const int row0 = bid * 16 + wid * 4;
        float4 v[4];
        float m[4];
#pragma unroll
        for (int r = 0; r < 4; ++r) {
            v[r] = ((const float4*)x)[(size_t)(row0 + r) * 64 + lane];
            m[r] = fmaxf(fmaxf(fabsf(v[r].x), fabsf(v[r].y)), fmaxf(fabsf(v[r].z), fabsf(v[r].w)));
        }
#pragma unroll
        for (int d = 1; d < 64; d <<= 1) {
#pragma unroll
            for (int r = 0; r < 4; ++r) m[r] = fmaxf(m[r], __shfl_xor(m[r], d, 64));
        }
#pragma unroll
        for (int r = 0; r < 4; ++r) {
            const float inv = (m[r] > 0.f) ? 127.0f / m[r] : 0.f;
            int q0 = (int)rintf(v[r].x * inv) + 128;
            int q1 = (int)rintf(v[r].y * inv) + 128;
            int q2 = (int)rintf(v[r].z * inv) + 128;
            int q3 = (int)rintf(v[r].w * inv) + 128;
            unsigned int pk = (unsigned int)q0 | ((unsigned int)q1 << 8)
                            | ((unsigned int)q2 << 16) | ((unsigned int)q3 << 24);
            xq[(size_t)(row0 + r) * 64 + lane] = pk;
            if (lane == 0) scl[row0 + r] = m[r] * (1.0f / 127.0f);
        }
    } else {
        const int row = bid - NB_X;        // s*256 + k
        const int s = row >> 8, k = row & 255;
        wt[((size_t)s * OUT_DIM + tid) * D_FEAT + k] = f2bf(W[(size_t)row * OUT_DIM + tid]);
    }
}

// ---------------- fill_win: scatter into per-window (XCD-local) sub-buckets ----------------
// window = blockIdx.x & 7: under round-robin dispatch each window is written by ONE
// XCD -> its 3.84 MB window + cursor slice stay L2-resident until kernel-end flush.
// Sub-bucket = one 64B line (16 records x 4B). lambda = 2 exact (deterministic
// edge partition), P(>16) ~ 1e-11.
__global__ void __launch_bounds__(256) fill_win(const int* __restrict__ src,
        const int* __restrict__ dst, const float* __restrict__ w, const float* __restrict__ scl,
        int* __restrict__ cur8, unsigned int* __restrict__ ep1) {
    const int i = blockIdx.x * 256 + threadIdx.x;
    if (i >= TOTAL_E) return;
    const int win = blockIdx.x & (NWIN - 1);
    const int s = i / N_EDGES;
    const int sv = src[i];
    const int b = s * N_NODES + dst[i];
    const int pos = atomicAdd(&cur8[win * NBUCKET + b], 1);
    if (pos < CAPX) {
        const float wq = w[i] * scl[sv];
        ep1[((size_t)win * NBUCKET + b) * CAPX + pos] =
            (unsigned int)sv | (((unsigned int)f2bf(wq)) << 16);
    }
}

// ---------------- compact: merge 8 sub-buckets -> contiguous CAP=64 records ----------------
// Half-wave (32 lanes) per bucket; 8 buckets per 256-thr block.
__global__ void __launch_bounds__(256) compact(const int* __restrict__ cur8,
        const unsigned int* __restrict__ ep1, int* __restrict__ cnt2,
        unsigned int* __restrict__ ep2) {
    const int b = blockIdx.x * 8 + (threadIdx.x >> 5);
    const int l32 = threadIdx.x & 31;

    int myc = 0;
    if (l32 < NWIN) {
        int c = cur8[l32 * NBUCKET + b];
        myc = (c > CAPX) ? CAPX : c;
    }
    int cx[NWIN], off[NWIN];
    int tot = 0;
#pragma unroll
    for (int xw = 0; xw < NWIN; ++xw) {
        cx[xw] = __shfl(myc, xw, 32);   // width 32: stay within the half-wave
        off[xw] = tot;
        tot += cx[xw];
    }
    if (tot > CAP) tot = CAP;

    for (int i = l32; i < tot; i += 32) {
        int xw = 0, idx = 0;
#pragma unroll
        for (int t = 0; t < NWIN; ++t) {
            if (i >= off[t] && i < off[t] + cx[t]) { xw = t; idx = i - off[t]; }
        }
        ep2[(size_t)b * CAP + i] = ep1[((size_t)xw * NBUCKET + b) * CAPX + idx];
    }
    if (l32 == 0) cnt2[b] = tot;
}

// ---------------- aggregate: one 32-lane half per bucket (r16-verified body) ----------------
__global__ void __launch_bounds__(256) aggregate(
        const unsigned char* __restrict__ xq, const int* __restrict__ cnt2,
        const unsigned int* __restrict__ epack, unsigned short* __restrict__ hb) {
    const int b = blockIdx.x * 8 + (threadIdx.x >> 5);
    const int l32 = threadIdx.x & 31;
    const int xoff = l32 * 8;
    const int s = b / N_NODES;
    const int node = b - s * N_NODES;

    int c = cnt2[b]; if (c > CAP) c = CAP;
    const unsigned int* ep = epack + (size_t)b * CAP;

    float a[8];
#pragma unroll
    for (int j = 0; j < 8; ++j) a[j] = 0.f;
    float sw = 0.f;

    int it = 0;
    for (; it + 3 < c; it += 4) {        // 4 independent 8B table loads in flight
        const uint4 pk = *(const uint4*)(ep + it);
        const uint2 u0 = *(const uint2*)(xq + ((size_t)(pk.x & 0xFFFFu) << 8) + xoff);
        const uint2 u1 = *(const uint2*)(xq + ((size_t)(pk.y & 0xFFFFu) << 8) + xoff);
        const uint2 u2 = *(const uint2*)(xq + ((size_t)(pk.z & 0xFFFFu) << 8) + xoff);
        const uint2 u3 = *(const uint2*)(xq + ((size_t)(pk.w & 0xFFFFu) << 8) + xoff);
        const float w0 = __uint_as_float(pk.x & 0xFFFF0000u);
        const float w1 = __uint_as_float(pk.y & 0xFFFF0000u);
        const float w2 = __uint_as_float(pk.z & 0xFFFF0000u);
        const float w3 = __uint_as_float(pk.w & 0xFFFF0000u);
        sw += w0 + w1 + w2 + w3;
#pragma unroll
        for (int j = 0; j < 4; ++j) {
            const int sh = 8 * j;
            a[j]     += w0 * (float)((u0.x >> sh) & 0xffu) + w1 * (float)((u1.x >> sh) & 0xffu)
                      + w2 * (float)((u2.x >> sh) & 0xffu) + w3 * (float)((u3.x >> sh) & 0xffu);
            a[4 + j] += w0 * (float)((u0.y >> sh) & 0xffu) + w1 * (float)((u1.y >> sh) & 0xffu)
                      + w2 * (float)((u2.y >> sh) & 0xffu) + w3 * (float)((u3.y >> sh) & 0xffu);
        }
    }
    for (; it < c; ++it) {               // <=3 cleanup iterations
        const unsigned int pe = ep[it];
        const uint2 u = *(const uint2*)(xq + ((size_t)(pe & 0xFFFFu) << 8) + xoff);
        const float wv = __uint_as_float(pe & 0xFFFF0000u);
        sw += wv;
#pragma unroll
        for (int j = 0; j < 4; ++j) {
            const int sh = 8 * j;
            a[j]     += wv * (float)((u.x >> sh) & 0xffu);
            a[4 + j] += wv * (float)((u.y >> sh) & 0xffu);
        }
    }

    ushort8 o;
    const float bias = 128.f * sw;
#pragma unroll
    for (int j = 0; j < 8; ++j) o[j] = f2bf(a[j] - bias);
    *(ushort8*)(hb + (size_t)node * KDIM + s * D_FEAT + xoff) = o;
}

// ---------------- gemm_h: BM=128 tile, LDS-staged B (unchanged, verified) ----------------
__global__ void __launch_bounds__(512) gemm_h(
        const unsigned short* __restrict__ hb, const unsigned short* __restrict__ wt,
        float* __restrict__ out) {
    __shared__ unsigned short bs[OUT_DIM][136];
    const int n0 = blockIdx.x * GM_ROWS;
    const int wid = threadIdx.x >> 6;
    const int lane = threadIdx.x & 63;
    const int cit = lane & 15;
    const int kgrp = (lane >> 4) * 8;
    const bool valid = (n0 + wid * 16) < N_NODES;
    const int arow_idx = valid ? (n0 + wid * 16 + cit) : 0;
    const short* arow = (const short*)hb + (size_t)arow_idx * KDIM + kgrp;

    f32x4 acc[16];
#pragma unroll
    for (int j = 0; j < 16; ++j) acc[j] = (f32x4){0.f, 0.f, 0.f, 0.f};

    for (int kc = 0; kc < 6; ++kc) {
        const int s = kc >> 1;
        const int kb = (kc & 1) * 128;
        if (kc) __syncthreads();
        for (int i = threadIdx.x; i < 4096; i += 512) {
            const int n = i >> 4;
            const int k8 = (i & 15) << 3;
            *(ushort8*)&bs[n][k8] =
                *(const ushort8*)(wt + ((size_t)s * OUT_DIM + n) * D_FEAT + kb + k8);
        }
        __syncthreads();

#pragma unroll
        for (int ks = 0; ks < 4; ++ks) {
            short8 av = *(const short8*)(arow + kc * 128 + ks * 32);
#pragma unroll
            for (int nt = 0; nt < 16; ++nt) {
                short8 bv = *(const short8*)&bs[nt * 16 + cit][ks * 32 + kgrp];
                acc[nt] = __builtin_amdgcn_mfma_f32_16x16x32_bf16(av, bv, acc[nt], 0, 0, 0);
            }
        }
    }

    if (valid) {
        const int rbase = (lane >> 4) * 4;
#pragma unroll
        for (int nt = 0; nt < 16; ++nt) {
            const int col = nt * 16 + cit;
#pragma unroll
            for (int r = 0; r < 4; ++r) {
                out[(size_t)(n0 + wid * 16 + rbase + r) * OUT_DIM + col] = acc[nt][r];
            }
        }
    }
}

extern "C" void kernel_launch(void* const* d_in, const int* in_sizes, int n_in,
                              void* d_out, int out_size, void* d_ws, size_t ws_size,
                              hipStream_t stream) {
    const float* x        = (const float*)d_in[0];
    const int*   edge_src = (const int*)d_in[1];
    const int*   edge_dst = (const int*)d_in[2];
    const float* edge_w   = (const float*)d_in[3];
    const float* W        = (const float*)d_in[4];
    float* out = (float*)d_out;

    char* ws = (char*)d_ws;
    unsigned int*   xq    = (unsigned int*)(ws);                 //  5,120,000 B
    float*          scl   = (float*)(ws + 5120000);              //     80,000 B
    unsigned short* wt    = (unsigned short*)(ws + 5200000);     //    393,216 B
    int*            cur8  = (int*)(ws + 5593216);                //  1,920,000 B (8 windows)
    int*            cnt2  = (int*)(ws + 7513216);                //    240,000 B
    unsigned int*   ep2   = (unsigned int*)(ws + 7753216);       // 15,360,000 B (CAP=64 compacted)
    unsigned int*   ep1   = (unsigned int*)(ws + 23113216);      // 30,720,000 B (8 win x CAPX=16)
    unsigned short* hb    = (unsigned short*)(ws + 23113216);    //   OVERLAY: ep1 dead after compact
    // total: 53,833,216 B

    hipMemsetAsync(cur8, 0, 1920000, stream);

    prep1<<<NB_X + NB_W, 256, 0, stream>>>(x, W, xq, scl, wt);
    fill_win<<<NB_F, 256, 0, stream>>>(edge_src, edge_dst, edge_w, scl, cur8, ep1);
    compact<<<NBUCKET / 8, 256, 0, stream>>>(cur8, ep1, cnt2, ep2);

    aggregate<<<NBUCKET / 8, 256, 0, stream>>>((const unsigned char*)xq, cnt2, ep2, hb);

    gemm_h<<<GM_BLOCKS, 512, 0, stream>>>(hb, wt, out);
}